// Round 1
// 490.192 us; speedup vs baseline: 1.0569x; 1.0569x over previous
//
#include <hip/hip_runtime.h>
#include <hip/hip_bf16.h>

// GN block on MI355X — FP32 I/O, bf16 MFMA internally, fused aggregation.
//
// e_new = relu(edge@We0 + P1[recv] + P2[send] + ce)   (MFMA, sorted-edge order)
// aggr  = segmented per-tile reduction + atomics (fused into k_edge)
// v_new = relu(aggr@Wv0 + Pv + cv)                    (MFMA)
// u_new = relu([mean_e, mean_v, u]@Wu + bu)
// P = node @ {We1,We2,Wv1} stored bf16 [n][384]. Weights bf16+transposed once.
//
// k_edge v2: 8-wave blocks (512 thr), We0^T in registers, P rows gathered
// via coalesced uint4 into LDS (replaces 64 scalar u16 loads/thread).

#define NN 20000
#define NE 320000
#define DD 128
#define SAS 136  // LDS stride (u16), pad 8 -> conflict-free b128
#define SBS 136
#define NBLK 512     // persistent blocks for k_edge (2 per CU x 256)
#define NTILE 5000   // NE/64

typedef unsigned short u16;
typedef __attribute__((ext_vector_type(8))) short bf16x8;
typedef __attribute__((ext_vector_type(4))) float f32x4;

__device__ __forceinline__ float b2f(unsigned short h) {
  return __uint_as_float(((unsigned int)h) << 16);
}
__device__ __forceinline__ unsigned short f2b(float f) {
  unsigned int u = __float_as_uint(f);
  unsigned int r = (u + 0x7fffu + ((u >> 16) & 1u)) >> 16;  // RNE
  return (unsigned short)r;
}

// --------------------------------------------------------- MFMA GEMM core
// (4-wave variant, used by k_mid / k_node)
__device__ __forceinline__ void mfma_core(const u16* sA, const u16* sBT,
                                          int lane, int w, f32x4 acc[4][2]) {
  int r15 = lane & 15;
  int koff = (lane >> 4) * 8;
#pragma unroll
  for (int k0 = 0; k0 < DD; k0 += 32) {
    bf16x8 a[4], b[2];
#pragma unroll
    for (int mt = 0; mt < 4; ++mt)
      a[mt] = *(const bf16x8*)&sA[(mt * 16 + r15) * SAS + k0 + koff];
#pragma unroll
    for (int nt = 0; nt < 2; ++nt)
      b[nt] = *(const bf16x8*)&sBT[(w * 32 + nt * 16 + r15) * SBS + k0 + koff];
#pragma unroll
    for (int mt = 0; mt < 4; ++mt)
#pragma unroll
      for (int nt = 0; nt < 2; ++nt)
        acc[mt][nt] = __builtin_amdgcn_mfma_f32_16x16x32_bf16(
            a[mt], b[nt], acc[mt][nt], 0, 0, 0);
  }
}

__device__ __forceinline__ void stage_w(u16* sBT, const u16* wsrc, int tid) {
  const uint4* ws = (const uint4*)wsrc;
  for (int i = tid; i < DD * DD / 8; i += 256) {
    int n = i >> 4, kk = (i & 15) * 8;
    *(uint4*)&sBT[n * SBS + kk] = ws[i];
  }
}

// --------------------------------------- setup: hist + weight prep + consts
__global__ __launch_bounds__(256) void k_setup(const int* recv, int* counts,
                                               const float* We, const float* Wv,
                                               const float* u, const float* be,
                                               const float* bv, u16* wt,
                                               float* ce, float* cv) {
  __shared__ float su[DD];
  int b = blockIdx.x, tid = threadIdx.x;
  if (b < 1250) {  // histogram (1250*256 == NE)
    atomicAdd(&counts[recv[b * 256 + tid]], 1);
  } else if (b < 1255) {  // transpose+bf16: 0:We0 1:We1 2:We2 3:Wv1 4:Wv0
    int m = b - 1250;
    const float* W = (m == 0)   ? We
                     : (m == 1) ? We + 128 * DD
                     : (m == 2) ? We + 256 * DD
                     : (m == 3) ? Wv + 128 * DD
                                : Wv;
    u16* o = wt + (size_t)m * DD * DD;
    for (int i = tid; i < DD * DD; i += 256) {
      int k = i >> 7, n = i & 127;
      o[n * DD + k] = f2b(W[i]);
    }
  } else {  // ce = u@We3+be, cv = u@Wv2+bv
    if (tid < DD) su[tid] = u[tid];
    __syncthreads();
    if (tid < DD) {
      float a = be[tid], c = bv[tid];
      for (int k = 0; k < DD; ++k) {
        a = fmaf(su[k], We[(384 + k) * DD + tid], a);
        c = fmaf(su[k], Wv[(256 + k) * DD + tid], c);
      }
      ce[tid] = a;
      cv[tid] = c;
    }
  }
}

// ---------------------------------------------------------------- CSR scan
__global__ void k_scan(const int* counts, int* rowptr, int* cursor) {
  __shared__ int wsum[16];
  __shared__ int carry;
  int tid = threadIdx.x;  // 1024
  int lane = tid & 63, wv = tid >> 6;
  if (tid == 0) carry = 0;
  __syncthreads();
  for (int base = 0; base < NN; base += 1024) {
    int i = base + tid;
    int v = (i < NN) ? counts[i] : 0;
    int x = v;
    for (int off = 1; off < 64; off <<= 1) {
      int t = __shfl_up(x, off);
      if (lane >= off) x += t;
    }
    if (lane == 63) wsum[wv] = x;
    __syncthreads();
    if (wv == 0 && lane < 16) {
      int y = wsum[lane];
      for (int off = 1; off < 16; off <<= 1) {
        int t = __shfl_up(y, off);
        if (lane >= off) y += t;
      }
      wsum[lane] = y;
    }
    __syncthreads();
    int woff = (wv > 0) ? wsum[wv - 1] : 0;
    int excl = carry + woff + (x - v);
    if (i < NN) {
      rowptr[i] = excl;
      cursor[i] = excl;
    }
    __syncthreads();
    if (tid == 0) carry += wsum[15];
    __syncthreads();
  }
  if (tid == 0) rowptr[NN] = carry;  // == NE
}

// ---------------------------------- mid: CSR fill + P = node @ {We1,We2,Wv1}
__global__ __launch_bounds__(256) void k_mid(const int* recv, int* cursor,
                                             int* elist, const float* node_attr,
                                             const u16* wt, u16* P) {
  __shared__ __align__(16) u16 sA[64 * SAS];
  __shared__ __align__(16) u16 sBT[DD * SBS];
  int b = blockIdx.x, tid = threadIdx.x;
  if (b < 1250) {  // fill
    int e = b * 256 + tid;
    int slot = atomicAdd(&cursor[recv[e]], 1);
    elist[slot] = e;
    return;
  }
  int n0 = (b - 1250) * 64;
  for (int i = tid; i < 64 * DD / 4; i += 256) {
    int rr = i >> 5, cc = (i & 31) * 4;
    float4 a4 = (n0 + rr < NN)
                    ? ((const float4*)node_attr)[(size_t)(n0 + rr) * 32 + (i & 31)]
                    : make_float4(0, 0, 0, 0);
    ushort4 h;
    h.x = f2b(a4.x); h.y = f2b(a4.y); h.z = f2b(a4.z); h.w = f2b(a4.w);
    *(ushort4*)&sA[rr * SAS + cc] = h;
  }
  int lane = tid & 63, w = tid >> 6;
  int c15 = lane & 15, quad = lane >> 4;
  int col0 = w * 32 + c15, col1 = col0 + 16;
  for (int sel = 0; sel < 3; ++sel) {
    __syncthreads();  // sA ready / prior sBT reads done
    stage_w(sBT, wt + (size_t)(1 + sel) * DD * DD, tid);
    __syncthreads();
    f32x4 acc[4][2] = {};
    mfma_core(sA, sBT, lane, w, acc);
#pragma unroll
    for (int mt = 0; mt < 4; ++mt)
#pragma unroll
      for (int r = 0; r < 4; ++r) {
        int n = n0 + mt * 16 + quad * 4 + r;
        if (n < NN) {
          u16* o = &P[(size_t)n * 384 + sel * 128];
          o[col0] = f2b(acc[mt][0][r]);
          o[col1] = f2b(acc[mt][1][r]);
        }
      }
  }
}

// ---------------------- edge block: persistent, pipelined, fused aggregation
// v2: 512 threads (8 waves), each wave owns 16 output cols; We0^T in regs;
// P[recv]/P[send] rows gathered cooperatively (uint4) into LDS.
__global__ __launch_bounds__(512, 4) void k_edge(const float* edge_attr,
                                                 const u16* wt, const int* elist,
                                                 const int* recv, const int* send,
                                                 const u16* P, const float* ce,
                                                 float* e_out, float* aggr,
                                                 float* sum_e) {
  __shared__ __align__(16) u16 sA[64 * SAS];   // A tile, then e_new (bf16)
  __shared__ __align__(16) u16 sPr[64 * SAS];  // gathered P[recv][0:128]
  __shared__ __align__(16) u16 sPs[64 * SAS];  // gathered P[send][128:256]
  __shared__ int sEid[64], sRecv[64], sSend[64];
  int tid = threadIdx.x;
  int lane = tid & 63, w = tid >> 6;  // 8 waves
  int r15 = lane & 15, quad = lane >> 4;
  int koff = quad * 8;
  int col0 = w * 16 + r15;     // this thread's output column
  int myrow = tid >> 5;        // A-staging rows: myrow + 16j
  int mycol = (tid & 31) * 4;  // f32 col offset (float4 chunk)

  // We0^T fragments for this wave's 16 columns -> 16 VGPRs
  bf16x8 breg[4];
#pragma unroll
  for (int kk = 0; kk < 4; ++kk)
    breg[kk] =
        *(const bf16x8*)&wt[(size_t)(w * 16 + r15) * DD + kk * 32 + koff];
  float ce0 = ce[col0];

  float4 areg[4];
  int eid4[4];
  int eidN = 0, rcN = 0, sdN = 0;
  int t = blockIdx.x;

  {  // prefetch tile t
    int base = t * 64;
#pragma unroll
    for (int j = 0; j < 4; ++j) eid4[j] = elist[base + myrow + 16 * j];
    if (tid < 64) {
      eidN = elist[base + tid];
      rcN = recv[eidN];
      sdN = send[eidN];
    }
#pragma unroll
    for (int j = 0; j < 4; ++j)
      areg[j] = *(const float4*)&edge_attr[(size_t)eid4[j] * DD + mycol];
  }
  float colsum = 0.f;  // threads 0..255 own (col, row-half)
  bool first = true;

  for (; t < NTILE; t += NBLK) {
    if (!first) __syncthreads();  // prev walk/copy done -> sA free
    first = false;
#pragma unroll
    for (int j = 0; j < 4; ++j) {
      ushort4 h;
      h.x = f2b(areg[j].x); h.y = f2b(areg[j].y);
      h.z = f2b(areg[j].z); h.w = f2b(areg[j].w);
      *(ushort4*)&sA[(myrow + 16 * j) * SAS + mycol] = h;
    }
    if (tid < 64) {
      sEid[tid] = eidN;
      sRecv[tid] = rcN;
      sSend[tid] = sdN;
    }
    __syncthreads();  // sA + meta ready

    // issue coalesced P-row gathers: 2048 uint4 (64 recv rows + 64 send rows)
    uint4 q[4];
    int pr_[4], pc_[4], ph_[4];
#pragma unroll
    for (int j = 0; j < 4; ++j) {
      int idx = tid + 512 * j;  // 0..2047
      int half = idx >> 10;     // 0: recv, 1: send
      int ii = idx & 1023;
      int row = ii >> 4, ch = ii & 15;
      const uint4* src =
          (half == 0) ? (const uint4*)&P[(size_t)sRecv[row] * 384] + ch
                      : (const uint4*)&P[(size_t)sSend[row] * 384 + 128] + ch;
      q[j] = *src;
      pr_[j] = row; pc_[j] = ch; ph_[j] = half;
    }
    int tn = t + NBLK;
    if (tn < NTILE) {  // prefetch next tile during compute
      int base = tn * 64;
#pragma unroll
      for (int j = 0; j < 4; ++j) eid4[j] = elist[base + myrow + 16 * j];
      if (tid < 64) {
        eidN = elist[base + tid];
        rcN = recv[eidN];
        sdN = send[eidN];
      }
#pragma unroll
      for (int j = 0; j < 4; ++j)
        areg[j] = *(const float4*)&edge_attr[(size_t)eid4[j] * DD + mycol];
    }

    f32x4 acc[4] = {};
#pragma unroll
    for (int kk = 0; kk < 4; ++kk) {
      bf16x8 a[4];
#pragma unroll
      for (int mt = 0; mt < 4; ++mt)
        a[mt] = *(const bf16x8*)&sA[(mt * 16 + r15) * SAS + kk * 32 + koff];
#pragma unroll
      for (int mt = 0; mt < 4; ++mt)
        acc[mt] = __builtin_amdgcn_mfma_f32_16x16x32_bf16(a[mt], breg[kk],
                                                          acc[mt], 0, 0, 0);
    }
    // land gathered P rows in LDS (compiler emits counted vmcnt for q only)
#pragma unroll
    for (int j = 0; j < 4; ++j) {
      u16* dst = (ph_[j] == 0) ? sPr : sPs;
      *(uint4*)&dst[pr_[j] * SAS + pc_[j] * 8] = q[j];
    }
    __syncthreads();  // sPr/sPs ready; all MFMA reads of sA done

    // epilogue: acc + P1 + P2 + ce, relu -> bf16 back into sA
#pragma unroll
    for (int mt = 0; mt < 4; ++mt)
#pragma unroll
      for (int r = 0; r < 4; ++r) {
        int m = mt * 16 + quad * 4 + r;
        float v = fmaxf(acc[mt][r] + b2f(sPr[m * SAS + col0]) +
                            b2f(sPs[m * SAS + col0]) + ce0,
                        0.f);
        sA[m * SAS + col0] = f2b(v);
      }
    __syncthreads();  // e_new (bf16) ready in sA

    if (tid < 256) {
      // waves 0-3: segmented column reduction, 2 row-halves x 128 cols
      int col = tid & 127, half = tid >> 7;
      int r0 = half * 32;
      float run = 0.f;
      int prev = sRecv[r0];
      for (int r = r0; r < r0 + 32; ++r) {
        int cur = sRecv[r];  // wave-uniform
        float v = b2f(sA[r * SAS + col]);
        if (cur != prev) {
          atomicAdd(&aggr[(size_t)prev * DD + col], run);
          run = 0.f;
          prev = cur;
        }
        run += v;
        colsum += v;
      }
      atomicAdd(&aggr[(size_t)prev * DD + col], run);
    } else {
      // waves 4-7: coalesced e_out row writes
      int tt = tid - 256;
#pragma unroll
      for (int j = 0; j < 4; ++j) {
        int i = tt + 256 * j;
        int row = i >> 4, ch = (i & 15) * 8;
        uint4 qq = *(const uint4*)&sA[row * SAS + ch];
        float4 f0, f1;
        f0.x = b2f((u16)(qq.x & 0xffff)); f0.y = b2f((u16)(qq.x >> 16));
        f0.z = b2f((u16)(qq.y & 0xffff)); f0.w = b2f((u16)(qq.y >> 16));
        f1.x = b2f((u16)(qq.z & 0xffff)); f1.y = b2f((u16)(qq.z >> 16));
        f1.z = b2f((u16)(qq.w & 0xffff)); f1.w = b2f((u16)(qq.w >> 16));
        float* dst = &e_out[(size_t)sEid[row] * DD + ch];
        *(float4*)dst = f0;
        *(float4*)(dst + 4) = f1;
      }
    }
  }
  if (tid < 256) atomicAdd(&sum_e[tid & 127], colsum);
}

// ------------------------------------------------------------- node block
__global__ __launch_bounds__(256) void k_node(const float* aggr, const u16* wt,
                                              const u16* P, const float* cv,
                                              float* v_out, float* sum_v) {
  __shared__ __align__(16) u16 sA[64 * SAS];
  __shared__ __align__(16) u16 sBT[DD * SBS];
  __shared__ float sCol[DD];
  int tid = threadIdx.x;
  int n0 = blockIdx.x * 64;
  stage_w(sBT, wt + (size_t)4 * DD * DD, tid);  // Wv0^T
  for (int i = tid; i < 64 * DD / 4; i += 256) {
    int rr = i >> 5, cc = (i & 31) * 4;
    float4 a4 = (n0 + rr < NN)
                    ? ((const float4*)aggr)[(size_t)(n0 + rr) * 32 + (i & 31)]
                    : make_float4(0, 0, 0, 0);
    ushort4 h;
    h.x = f2b(a4.x); h.y = f2b(a4.y); h.z = f2b(a4.z); h.w = f2b(a4.w);
    *(ushort4*)&sA[rr * SAS + cc] = h;
  }
  if (tid < DD) sCol[tid] = 0.f;
  __syncthreads();
  int lane = tid & 63, w = tid >> 6;
  f32x4 acc[4][2] = {};
  mfma_core(sA, sBT, lane, w, acc);
  int c15 = lane & 15, quad = lane >> 4;
  int col0 = w * 32 + c15, col1 = col0 + 16;
  float cv0 = cv[col0], cv1 = cv[col1];
  float cs0 = 0.f, cs1 = 0.f;
#pragma unroll
  for (int mt = 0; mt < 4; ++mt)
#pragma unroll
    for (int r = 0; r < 4; ++r) {
      int n = n0 + mt * 16 + quad * 4 + r;
      if (n < NN) {
        const u16* pv = &P[(size_t)n * 384 + 256];
        float v0 = fmaxf(acc[mt][0][r] + b2f(pv[col0]) + cv0, 0.f);
        float v1 = fmaxf(acc[mt][1][r] + b2f(pv[col1]) + cv1, 0.f);
        size_t ob = (size_t)n * DD;
        v_out[ob + col0] = v0;
        v_out[ob + col1] = v1;
        cs0 += v0;
        cs1 += v1;
      }
    }
  atomicAdd(&sCol[col0], cs0);
  atomicAdd(&sCol[col1], cs1);
  __syncthreads();
  if (tid < DD) atomicAdd(&sum_v[tid], sCol[tid]);
}

// ------------------------------------------------------------ global block
__global__ void k_global(const float* sumbuf, const float* u, const float* Wu,
                         const float* bu, float* out) {
  __shared__ float sin_[384];
  int j = threadIdx.x;  // 128
  sin_[j] = sumbuf[j] * (1.0f / (float)NE);
  sin_[128 + j] = sumbuf[128 + j] * (1.0f / (float)NN);
  sin_[256 + j] = u[j];
  __syncthreads();
  float a = bu[j];
  for (int k = 0; k < 384; ++k) a = fmaf(sin_[k], Wu[k * DD + j], a);
  out[j] = fmaxf(a, 0.f);
}

// ---------------------------------------------------------------- launcher
extern "C" void kernel_launch(void* const* d_in, const int* in_sizes, int n_in,
                              void* d_out, int out_size, void* d_ws,
                              size_t ws_size, hipStream_t stream) {
  const float* edge_attr = (const float*)d_in[0];
  const float* node_attr = (const float*)d_in[1];
  const float* u = (const float*)d_in[2];
  const int* senders = (const int*)d_in[3];
  const int* receivers = (const int*)d_in[4];
  const float* We = (const float*)d_in[5];
  const float* be = (const float*)d_in[6];
  const float* Wv = (const float*)d_in[7];
  const float* bv = (const float*)d_in[8];
  const float* Wu = (const float*)d_in[9];
  const float* bu = (const float*)d_in[10];

  float* e_out = (float*)d_out;
  float* v_out = e_out + (size_t)NE * DD;
  float* u_out = v_out + (size_t)NN * DD;

  // workspace layout (4B units); [counts|sumbuf|aggr] zeroed in one memset
  int* counts = (int*)d_ws;                       // NN
  float* sumbuf = (float*)d_ws + NN;              // 256
  float* aggr = (float*)d_ws + NN + 256;          // NN*128 (16B-aligned)
  int* rowptr = (int*)d_ws + NN + 256 + NN * DD;  // NN+1
  int* cursor = rowptr + NN + 1;                  // NN
  int* elist = cursor + NN;                       // NE
  size_t off = (size_t)(NN + 256 + NN * DD + (NN + 1) + NN + NE);
  off = (off + 3) & ~(size_t)3;                // 16B align
  u16* wt = (u16*)((float*)d_ws + off);        // 5*128*128 u16
  u16* P = wt + (size_t)5 * DD * DD;           // NN*384 u16
  float* ce = (float*)(P + (size_t)NN * 384);  // 128
  float* cv = ce + 128;                        // 128

  hipMemsetAsync(d_ws, 0, (size_t)(NN + 256 + NN * DD) * 4, stream);
  k_setup<<<1256, 256, 0, stream>>>(receivers, counts, We, Wv, u, be, bv, wt,
                                    ce, cv);
  k_scan<<<1, 1024, 0, stream>>>(counts, rowptr, cursor);
  k_mid<<<1250 + 313, 256, 0, stream>>>(receivers, cursor, elist, node_attr,
                                        wt, P);
  k_edge<<<NBLK, 512, 0, stream>>>(edge_attr, wt, elist, receivers, senders, P,
                                   ce, e_out, aggr, sumbuf);
  k_node<<<(NN + 63) / 64, 256, 0, stream>>>(aggr, wt, P, cv, v_out,
                                             sumbuf + 128);
  k_global<<<1, 128, 0, stream>>>(sumbuf, u, Wu, bu, u_out);
}